// Round 16
// baseline (468.950 us; speedup 1.0000x reference)
//
#include <hip/hip_runtime.h>
#include <cstddef>

#define HW   512
#define NPIX (HW*HW)
#define NP   (NPIX + 64)     // f32 plane stride
#define NC   21

typedef unsigned int u32;
typedef __fp16 h2 __attribute__((ext_vector_type(2)));
typedef float f32x2 __attribute__((ext_vector_type(2)));

#if defined(__has_builtin)
#if __has_builtin(__builtin_amdgcn_cvt_pk_f32_fp8) && __has_builtin(__builtin_amdgcn_cvt_pk_fp8_f32)
#define HAVE_FP8 1
#endif
#endif
#ifndef HAVE_FP8
#define HAVE_FP8 0
#endif

#if HAVE_FP8
#define WSLOT 1792           // u32 per (a,dyi) slot: 128 thr x 14 u32 (fp8)
#else
#define WSLOT 3584           // u32 per slot: 128 thr x 28 u32 (fp16 pairs)
#endif

__device__ __forceinline__ float fexp2(float x) { return __builtin_amdgcn_exp2f(x); }
__device__ __forceinline__ h2 as_h2(u32 x) { union { u32 u; h2 h; } v; v.u = x; return v.h; }
__device__ __forceinline__ u32 as_u32(h2 x) { union { h2 h; u32 u; } v; v.h = x; return v.u; }
__device__ __forceinline__ u32 pkrtz(float a, float b) { return as_u32(__builtin_amdgcn_cvt_pkrtz(a, b)); }

// dot over 7 packed fp16 pairs: s += sum_t w[t] . a[t]
__device__ __forceinline__ float dot7(const u32* w, const u32* a, float s) {
    #pragma unroll
    for (int t = 0; t < 7; ++t)
        s = __builtin_amdgcn_fdot2(as_h2(w[t]), as_h2(a[t]), s, false);
    return s;
}

#define KB_EXP (-0.08014972449f)          /* -0.5/9 * log2(e) */
#define LOG2E  (1.4426950408889634f)

#define KSP_INIT {0.13533528f, 0.24935221f, 0.41111229f, 0.60653066f, 0.80073740f, \
                  0.94595947f, 1.00000000f, 0.94595947f, 0.80073740f, 0.60653066f, \
                  0.41111229f, 0.24935221f, 0.13533528f}

// ---------- setup ----------
__global__ void k_setup(const float* __restrict__ unaries, const float* __restrict__ rgb,
                        float* __restrict__ u, float* q, float* __restrict__ rgbT,
                        _Float16* u16) {
    int p = blockIdx.x * 256 + threadIdx.x;       // p = a*512 + b
    int a = p >> 9, b = p & 511;
    int src = b * 512 + a;
    #pragma unroll
    for (int c = 0; c < NC; ++c) {
        float v = unaries[src * NC + c];
        u[c * NP + p] = v;
        if (q)   q[c * NP + p] = v;
        if (u16) u16[(size_t)c * NPIX + p] = (_Float16)v;
    }
    #pragma unroll
    for (int ch = 0; ch < 3; ++ch) rgbT[ch * NP + p] = rgb[src * 3 + ch];
}

// ---------- prep ----------
__global__ void k_prep(const float* __restrict__ Wsp, const float* __restrict__ Wbl,
                       const float* __restrict__ Cm,
                       float* __restrict__ invS, float* __restrict__ M1, float* __restrict__ M2) {
    int t = threadIdx.x;
    const float KSP[13] = KSP_INIT;
    {
        float s = 0.f;
        #pragma unroll
        for (int d = 0; d < 13; ++d) {
            int i = t + d - 6;
            if ((unsigned)i < 512u) s += KSP[d];
        }
        invS[t] = 1.0f / s;
    }
    if (t < NC * NC) {
        int c = t / NC, j = t % NC;
        float s1 = 0.f, s2 = 0.f;
        for (int k = 0; k < NC; ++k) {
            float cm = Cm[c * NC + k];
            s1 += cm * Wsp[k * NC + j];
            s2 += cm * Wbl[k * NC + j];
        }
        M1[t] = -s1;
        M2[t] = -s2;
    }
}

// ---------- one-time: precompute bilateral weights, 4 dy-quarters ----------
// fp8: u32 k holds pairs 2k (lo16) and 2k+1 (hi16); norm from DEQUANTIZED w.
__global__ void k_weights_part(const float* __restrict__ rgbT, u32* __restrict__ wbuf,
                               float* __restrict__ nq) {
    int bid = blockIdx.x;
    int z = bid >> 9, a = bid & 511;
    int b0 = threadIdx.x << 2;
    float cr[3][4];
    #pragma unroll
    for (int ch = 0; ch < 3; ++ch) {
        float4 f = *reinterpret_cast<const float4*>(rgbT + ch * NP + a * HW + b0);
        cr[ch][0] = f.x; cr[ch][1] = f.y; cr[ch][2] = f.z; cr[ch][3] = f.w;
    }
    float nsum[4] = {0.f, 0.f, 0.f, 0.f};
    const int dlos[4] = {0, 3, 7, 10};
    const int dhis[4] = {3, 7, 10, 13};
    int dlo = dlos[z], dhi = dhis[z];
    #pragma unroll 1
    for (int dyi = dlo; dyi < dhi; ++dyi) {
        int ar = a + dyi - 6;
        if ((unsigned)ar >= 512u) continue;
        float nr[3][20];
        #pragma unroll
        for (int ch = 0; ch < 3; ++ch)
            #pragma unroll
            for (int tq = 0; tq < 5; ++tq) {
                float4 f = *reinterpret_cast<const float4*>(rgbT + ch * NP + ar * HW + b0 - 8 + 4 * tq);
                nr[ch][4*tq+0] = f.x; nr[ch][4*tq+1] = f.y; nr[ch][4*tq+2] = f.z; nr[ch][4*tq+3] = f.w;
            }
        float spk = KB_EXP * (float)((dyi - 6) * (dyi - 6));
        float pw[28][2];
        #pragma unroll
        for (int j = 0; j < 4; ++j) {
            float w[13];
            #pragma unroll
            for (int dx = 0; dx < 13; ++dx) {
                int ic = j + dx + 2;
                float d0 = cr[0][j] - nr[0][ic];
                float d1 = cr[1][j] - nr[1][ic];
                float d2 = cr[2][j] - nr[2][ic];
                float dcol = d0*d0 + d1*d1 + d2*d2;
                float arg = KB_EXP * dcol + (spk + KB_EXP * (float)((dx-6)*(dx-6)));
                bool ok = (unsigned)(b0 + j + dx - 6) < 512u;
                w[dx] = ok ? fexp2(arg) : 0.f;
            }
            #pragma unroll
            for (int t = 0; t < 6; ++t) { pw[j*7+t][0] = w[2*t]; pw[j*7+t][1] = w[2*t+1]; }
            pw[j*7+6][0] = w[12]; pw[j*7+6][1] = 0.f;
        }
#if HAVE_FP8
        uint2* dst = reinterpret_cast<uint2*>(wbuf + (size_t)(a * 13 + dyi) * WSLOT) + threadIdx.x * 7;
        #pragma unroll
        for (int k = 0; k < 7; ++k) {
            u32 vx = (u32)__builtin_amdgcn_cvt_pk_fp8_f32(pw[4*k][0],   pw[4*k][1],   0, false);
            vx     = (u32)__builtin_amdgcn_cvt_pk_fp8_f32(pw[4*k+1][0], pw[4*k+1][1], (int)vx, true);
            u32 vy = (u32)__builtin_amdgcn_cvt_pk_fp8_f32(pw[4*k+2][0], pw[4*k+2][1], 0, false);
            vy     = (u32)__builtin_amdgcn_cvt_pk_fp8_f32(pw[4*k+3][0], pw[4*k+3][1], (int)vy, true);
            f32x2 da = __builtin_amdgcn_cvt_pk_f32_fp8((int)vx, false);
            f32x2 db = __builtin_amdgcn_cvt_pk_f32_fp8((int)vx, true);
            f32x2 dc = __builtin_amdgcn_cvt_pk_f32_fp8((int)vy, false);
            f32x2 dd = __builtin_amdgcn_cvt_pk_f32_fp8((int)vy, true);
            nsum[(4*k)   / 7] += da.x + da.y;
            nsum[(4*k+1) / 7] += db.x + db.y;
            nsum[(4*k+2) / 7] += dc.x + dc.y;
            nsum[(4*k+3) / 7] += dd.x + dd.y;
            dst[k] = make_uint2(vx, vy);
        }
#else
        u32 arr[28];
        #pragma unroll
        for (int p = 0; p < 28; ++p) {
            arr[p] = pkrtz(pw[p][0], pw[p][1]);
            nsum[p / 7] += pw[p][0] + pw[p][1];
        }
        uint4* dst = reinterpret_cast<uint4*>(wbuf + (size_t)(a * 13 + dyi) * WSLOT) + threadIdx.x * 7;
        #pragma unroll
        for (int k = 0; k < 7; ++k)
            dst[k] = make_uint4(arr[4*k], arr[4*k+1], arr[4*k+2], arr[4*k+3]);
#endif
    }
    float4 r; r.x = nsum[0]; r.y = nsum[1]; r.z = nsum[2]; r.w = nsum[3];
    *reinterpret_cast<float4*>(nq + (size_t)z * NP + a * HW + b0) = r;
}

__global__ void k_invnorm(const float* __restrict__ nq, float* __restrict__ inorm) {
    int i = blockIdx.x * 256 + threadIdx.x;
    inorm[i] = 1.0f / (nq[i] + nq[NP + i] + nq[2 * (size_t)NP + i] + nq[3 * (size_t)NP + i]);
}

// ---------- fused per-iter filters: bilateral (from wbuf) + non-separable spatial ----------
// grid 1536 = 8 XCD x (64 rows x 3 chunks); 128 thr, 4 px/thread, all 13 dy.
__global__ __launch_bounds__(128, 3)
void k_filters(const _Float16* __restrict__ ph, const u32* __restrict__ wbuf,
               const float* __restrict__ invS,
               _Float16* __restrict__ P, _Float16* __restrict__ SP) {
    int bid = blockIdx.x;
    int xj = bid & 7;          // XCD
    int g  = bid >> 3;         // 0..191
    int rl = g / 3;            // local row
    int y  = g - rl * 3;       // chunk
    int a  = xj * 64 + rl;
    int cbase = y * 7;
    int tid = threadIdx.x;
    int b0  = tid << 2;

    // spatial packed weights, per-j edge-masked (same dot7 alignment as bilateral)
    const float KSP[13] = KSP_INIT;
    u32 kp[4][7];
    #pragma unroll
    for (int j = 0; j < 4; ++j) {
        float wj[13];
        #pragma unroll
        for (int dx = 0; dx < 13; ++dx) {
            bool ok = (unsigned)(b0 + j + dx - 6) < 512u;
            wj[dx] = ok ? KSP[dx] : 0.f;
        }
        #pragma unroll
        for (int t = 0; t < 6; ++t) kp[j][t] = pkrtz(wj[2*t], wj[2*t+1]);
        kp[j][6] = pkrtz(wj[12], 0.f);
    }

    float acc[7][4], spa[7][4];
    #pragma unroll
    for (int ci = 0; ci < 7; ++ci)
        #pragma unroll
        for (int j = 0; j < 4; ++j) { acc[ci][j] = 0.f; spa[ci][j] = 0.f; }

    #pragma unroll 1
    for (int dyi = 0; dyi < 13; ++dyi) {
        int ar = a + dyi - 6;
        if ((unsigned)ar >= 512u) continue;
        float kdy = fexp2(KB_EXP * (float)((dyi - 6) * (dyi - 6)));
        u32 arr[28];
#if HAVE_FP8
        const uint2* wp = reinterpret_cast<const uint2*>(wbuf + (size_t)(a * 13 + dyi) * WSLOT) + tid * 7;
        #pragma unroll
        for (int k = 0; k < 7; ++k) {
            uint2 v = wp[k];
            f32x2 da = __builtin_amdgcn_cvt_pk_f32_fp8((int)v.x, false);
            f32x2 db = __builtin_amdgcn_cvt_pk_f32_fp8((int)v.x, true);
            f32x2 dc = __builtin_amdgcn_cvt_pk_f32_fp8((int)v.y, false);
            f32x2 dd = __builtin_amdgcn_cvt_pk_f32_fp8((int)v.y, true);
            arr[4*k]   = pkrtz(da.x, da.y);
            arr[4*k+1] = pkrtz(db.x, db.y);
            arr[4*k+2] = pkrtz(dc.x, dc.y);
            arr[4*k+3] = pkrtz(dd.x, dd.y);
        }
#else
        const uint4* wp = reinterpret_cast<const uint4*>(wbuf + (size_t)(a * 13 + dyi) * WSLOT) + tid * 7;
        #pragma unroll
        for (int k = 0; k < 7; ++k) {
            uint4 wv = wp[k];
            arr[4*k] = wv.x; arr[4*k+1] = wv.y; arr[4*k+2] = wv.z; arr[4*k+3] = wv.w;
        }
#endif
        #pragma unroll
        for (int ci = 0; ci < 7; ++ci) {
            const uint2* pw = reinterpret_cast<const uint2*>(ph + (size_t)(cbase + ci) * NPIX + ar * HW + b0 - 8);
            uint2 L0 = pw[0], L1 = pw[1], L2 = pw[2], L3 = pw[3], L4 = pw[4];
            u32 W0[10] = {L0.x, L0.y, L1.x, L1.y, L2.x, L2.y, L3.x, L3.y, L4.x, L4.y};
            u32 W1[9];
            #pragma unroll
            for (int k = 1; k < 9; ++k) W1[k] = (W0[k] >> 16) | (W0[k+1] << 16);
            acc[ci][0] = dot7(arr + 0,  W0 + 1, acc[ci][0]);
            acc[ci][1] = dot7(arr + 7,  W1 + 1, acc[ci][1]);
            acc[ci][2] = dot7(arr + 14, W0 + 2, acc[ci][2]);
            acc[ci][3] = dot7(arr + 21, W1 + 2, acc[ci][3]);
            spa[ci][0] = fmaf(kdy, dot7(kp[0], W0 + 1, 0.f), spa[ci][0]);
            spa[ci][1] = fmaf(kdy, dot7(kp[1], W1 + 1, 0.f), spa[ci][1]);
            spa[ci][2] = fmaf(kdy, dot7(kp[2], W0 + 2, 0.f), spa[ci][2]);
            spa[ci][3] = fmaf(kdy, dot7(kp[3], W1 + 2, 0.f), spa[ci][3]);
        }
    }
    float isa = invS[a];
    float4 iv = *reinterpret_cast<const float4*>(invS + b0);
    #pragma unroll
    for (int ci = 0; ci < 7; ++ci) {
        uint2 st;
        st.x = pkrtz(acc[ci][0], acc[ci][1]);
        st.y = pkrtz(acc[ci][2], acc[ci][3]);
        *reinterpret_cast<uint2*>(P + (size_t)(cbase + ci) * NPIX + a * HW + b0) = st;
        uint2 ss;
        ss.x = pkrtz(spa[ci][0] * isa * iv.x, spa[ci][1] * isa * iv.y);
        ss.y = pkrtz(spa[ci][2] * isa * iv.z, spa[ci][3] * isa * iv.w);
        *reinterpret_cast<uint2*>(SP + (size_t)(cbase + ci) * NPIX + a * HW + b0) = ss;
    }
}

// ---------- fused combine + softmax, 2 px/thread vectorized ----------
__global__ __launch_bounds__(128)
void k_combine2(const float* __restrict__ u, const _Float16* __restrict__ u16,
                const _Float16* __restrict__ sp, const _Float16* __restrict__ P,
                const float* __restrict__ inorm,
                const float* __restrict__ M1, const float* __restrict__ M2,
                _Float16* __restrict__ phout, float* __restrict__ out, int last) {
    __shared__ float m1[NC * NC], m2[NC * NC];
    int t = threadIdx.x;
    for (int i = t; i < NC * NC; i += 128) { m1[i] = M1[i]; m2[i] = M2[i]; }
    __syncthreads();
    int px = (blockIdx.x * 128 + t) << 1;
    float2 rn = *reinterpret_cast<const float2*>(inorm + px);
    float msg[NC][2];
    #pragma unroll
    for (int c = 0; c < NC; ++c) { msg[c][0] = 0.f; msg[c][1] = 0.f; }
    #pragma unroll 3
    for (int k = 0; k < NC; ++k) {
        h2 sh = as_h2(*reinterpret_cast<const u32*>(sp + (size_t)k * NPIX + px));
        h2 bh = as_h2(*reinterpret_cast<const u32*>(P  + (size_t)k * NPIX + px));
        float s0 = (float)sh[0], s1 = (float)sh[1];
        float b0 = (float)bh[0] * rn.x, b1 = (float)bh[1] * rn.y;
        #pragma unroll
        for (int c = 0; c < NC; ++c) {
            float a1 = m1[c * NC + k], a2 = m2[c * NC + k];
            msg[c][0] += a1 * s0 + a2 * b0;
            msg[c][1] += a1 * s1 + a2 * b1;
        }
    }
    if (last) {
        #pragma unroll
        for (int c = 0; c < NC; ++c) {
            float2 uu = *reinterpret_cast<const float2*>(u + c * NP + px);
            out[(size_t)px * NC + c]       = uu.x + msg[c][0];
            out[(size_t)(px + 1) * NC + c] = uu.y + msg[c][1];
        }
    } else {
        float q0[NC], q1[NC];
        #pragma unroll
        for (int c = 0; c < NC; ++c) {
            h2 uh = as_h2(*reinterpret_cast<const u32*>(u16 + (size_t)c * NPIX + px));
            q0[c] = (float)uh[0] + msg[c][0];
            q1[c] = (float)uh[1] + msg[c][1];
        }
        float m0 = -1e30f, m1v = -1e30f;
        #pragma unroll
        for (int c = 0; c < NC; ++c) { m0 = fmaxf(m0, q0[c]); m1v = fmaxf(m1v, q1[c]); }
        float s0 = 0.f, s1 = 0.f;
        #pragma unroll
        for (int c = 0; c < NC; ++c) {
            q0[c] = fexp2((q0[c] - m0) * LOG2E);  s0 += q0[c];
            q1[c] = fexp2((q1[c] - m1v) * LOG2E); s1 += q1[c];
        }
        float r0 = 1.0f / s0, r1 = 1.0f / s1;
        #pragma unroll
        for (int c = 0; c < NC; ++c)
            *reinterpret_cast<u32*>(phout + (size_t)c * NPIX + px) = pkrtz(q0[c] * r0, q1[c] * r1);
    }
}

// ---------- softmax (prologue + fallback), 4 px/thread ----------
__global__ void k_softmax(const float* __restrict__ q, _Float16* __restrict__ ph) {
    int i4 = (blockIdx.x * 256 + threadIdx.x) << 2;
    float v[NC][4];
    float m[4] = {-1e30f, -1e30f, -1e30f, -1e30f};
    #pragma unroll
    for (int c = 0; c < NC; ++c) {
        float4 f = *reinterpret_cast<const float4*>(q + c * NP + i4);
        v[c][0] = f.x; v[c][1] = f.y; v[c][2] = f.z; v[c][3] = f.w;
        #pragma unroll
        for (int j = 0; j < 4; ++j) m[j] = fmaxf(m[j], v[c][j]);
    }
    float s[4] = {0.f, 0.f, 0.f, 0.f};
    #pragma unroll
    for (int c = 0; c < NC; ++c)
        #pragma unroll
        for (int j = 0; j < 4; ++j) { v[c][j] = fexp2((v[c][j] - m[j]) * LOG2E); s[j] += v[c][j]; }
    float r[4];
    #pragma unroll
    for (int j = 0; j < 4; ++j) r[j] = 1.0f / s[j];
    #pragma unroll
    for (int c = 0; c < NC; ++c) {
        uint2 st;
        st.x = pkrtz(v[c][0] * r[0], v[c][1] * r[1]);
        st.y = pkrtz(v[c][2] * r[2], v[c][3] * r[3]);
        *reinterpret_cast<uint2*>(ph + (size_t)c * NPIX + i4) = st;
    }
}

// ================= fallback path kernels (ws too small for weight table) =================
__global__ void k_blnorm_part(const float* __restrict__ rgbT, float* __restrict__ nq) {
    int bid = blockIdx.x;
    int z = bid >> 9, a = bid & 511;
    int b0 = threadIdx.x << 2;
    float cr[3][4];
    #pragma unroll
    for (int ch = 0; ch < 3; ++ch) {
        float4 f = *reinterpret_cast<const float4*>(rgbT + ch * NP + a * HW + b0);
        cr[ch][0] = f.x; cr[ch][1] = f.y; cr[ch][2] = f.z; cr[ch][3] = f.w;
    }
    float sum[4] = {0.f, 0.f, 0.f, 0.f};
    const int dylos[4] = {-6, -3, 1, 4};
    const int dyhis[4] = {-4,  0, 3, 6};
    int dylo = dylos[z], dyhi = dyhis[z];
    #pragma unroll 1
    for (int dy = dylo; dy <= dyhi; ++dy) {
        int ar = a + dy;
        if ((unsigned)ar >= 512u) continue;
        int rowoff = ar * HW + b0 - 8;
        float nr[3][20];
        #pragma unroll
        for (int ch = 0; ch < 3; ++ch)
            #pragma unroll
            for (int tq = 0; tq < 5; ++tq) {
                float4 f = *reinterpret_cast<const float4*>(rgbT + ch * NP + rowoff + 4 * tq);
                nr[ch][4*tq+0] = f.x; nr[ch][4*tq+1] = f.y; nr[ch][4*tq+2] = f.z; nr[ch][4*tq+3] = f.w;
            }
        float spk = KB_EXP * (float)(dy * dy);
        #pragma unroll
        for (int j = 0; j < 4; ++j) {
            #pragma unroll
            for (int dx = 0; dx < 13; ++dx) {
                int ic = j + dx + 2;
                float d0 = cr[0][j] - nr[0][ic];
                float d1 = cr[1][j] - nr[1][ic];
                float d2 = cr[2][j] - nr[2][ic];
                float dcol = d0*d0 + d1*d1 + d2*d2;
                float arg = KB_EXP * dcol + (spk + KB_EXP * (float)((dx-6)*(dx-6)));
                bool ok = (unsigned)(b0 + j + dx - 6) < 512u;
                sum[j] += ok ? fexp2(arg) : 0.f;
            }
        }
    }
    float4 r; r.x = sum[0]; r.y = sum[1]; r.z = sum[2]; r.w = sum[3];
    *reinterpret_cast<float4*>(nq + (size_t)z * NP + a * HW + b0) = r;
}

__global__ void k_spatial_h(const _Float16* __restrict__ ph, _Float16* __restrict__ dst) {
    int idx = blockIdx.x * 256 + threadIdx.x;
    int b0 = (idx & 127) << 2;
    int a  = (idx >> 7) & 511;
    int c  = idx >> 16;
    const uint2* pw = reinterpret_cast<const uint2*>(ph + (size_t)c * NPIX + a * HW + b0 - 8);
    uint2 L0 = pw[0], L1 = pw[1], L2 = pw[2], L3 = pw[3], L4 = pw[4];
    u32 W0[10] = {L0.x, L0.y, L1.x, L1.y, L2.x, L2.y, L3.x, L3.y, L4.x, L4.y};
    const float KSP[13] = KSP_INIT;
    float out[4];
    if (b0 >= 8 && b0 <= 500) {
        u32 W1[9];
        #pragma unroll
        for (int k = 1; k < 9; ++k) W1[k] = (W0[k] >> 16) | (W0[k+1] << 16);
        u32 kp[7];
        #pragma unroll
        for (int t = 0; t < 6; ++t) kp[t] = pkrtz(KSP[2*t], KSP[2*t+1]);
        kp[6] = pkrtz(KSP[12], 0.f);
        out[0] = dot7(kp, W0 + 1, 0.f);
        out[1] = dot7(kp, W1 + 1, 0.f);
        out[2] = dot7(kp, W0 + 2, 0.f);
        out[3] = dot7(kp, W1 + 2, 0.f);
    } else {
        float pv[20];
        #pragma unroll
        for (int k = 0; k < 10; ++k) { h2 hh = as_h2(W0[k]); pv[2*k] = (float)hh[0]; pv[2*k+1] = (float)hh[1]; }
        #pragma unroll
        for (int j = 0; j < 4; ++j) out[j] = 0.f;
        #pragma unroll
        for (int d = 0; d < 13; ++d)
            #pragma unroll
            for (int j = 0; j < 4; ++j) {
                bool ok = (unsigned)(b0 + j + d - 6) < 512u;
                out[j] += (ok ? KSP[d] : 0.f) * pv[j + d + 2];
            }
    }
    uint2 st;
    st.x = pkrtz(out[0], out[1]);
    st.y = pkrtz(out[2], out[3]);
    *reinterpret_cast<uint2*>(dst + (size_t)c * NPIX + a * HW + b0) = st;
}

__global__ void k_spatial_v(const _Float16* __restrict__ src, _Float16* __restrict__ dst,
                            const float* __restrict__ invS) {
    int idx = blockIdx.x * 256 + threadIdx.x;
    int b0 = (idx & 127) << 2;
    int a  = (idx >> 7) & 511;
    int c  = idx >> 16;
    const float KSP[13] = KSP_INIT;
    float out[4] = {0.f, 0.f, 0.f, 0.f};
    #pragma unroll
    for (int d = 0; d < 13; ++d) {
        int ar = a + d - 6;
        if ((unsigned)ar < 512u) {
            uint2 L = *reinterpret_cast<const uint2*>(src + (size_t)c * NPIX + ar * HW + b0);
            h2 h0 = as_h2(L.x), h1 = as_h2(L.y);
            out[0] += KSP[d] * (float)h0[0]; out[1] += KSP[d] * (float)h0[1];
            out[2] += KSP[d] * (float)h1[0]; out[3] += KSP[d] * (float)h1[1];
        }
    }
    float isa = invS[a];
    float4 iv = *reinterpret_cast<const float4*>(invS + b0);
    uint2 st;
    st.x = pkrtz(out[0] * isa * iv.x, out[1] * isa * iv.y);
    st.y = pkrtz(out[2] * isa * iv.z, out[3] * isa * iv.w);
    *reinterpret_cast<uint2*>(dst + (size_t)c * NPIX + a * HW + b0) = st;
}

__global__ __launch_bounds__(128, 4)
void k_bilateral(const _Float16* __restrict__ ph, const float* __restrict__ rgbT,
                 float* __restrict__ P0, float* __restrict__ P1) {
    int bid = blockIdx.x;
    int xj = bid & 7;
    int g  = bid >> 3;
    int rl = g / 6;
    int v  = g - rl * 6;
    int a  = xj * 64 + rl;
    int y  = v >> 1;
    int z  = v & 1;
    int cbase = y * 7;
    int b0  = threadIdx.x << 2;
    float cr[3][4];
    #pragma unroll
    for (int ch = 0; ch < 3; ++ch) {
        float4 f = *reinterpret_cast<const float4*>(rgbT + ch * NP + a * HW + b0);
        cr[ch][0] = f.x; cr[ch][1] = f.y; cr[ch][2] = f.z; cr[ch][3] = f.w;
    }
    float acc[7][4];
    #pragma unroll
    for (int ci = 0; ci < 7; ++ci)
        #pragma unroll
        for (int j2 = 0; j2 < 4; ++j2) acc[ci][j2] = 0.f;

    int dylo = z ? 1 : -6, dyhi = z ? 6 : 0;
    #pragma unroll 1
    for (int dy = dylo; dy <= dyhi; ++dy) {
        int ar = a + dy;
        if ((unsigned)ar >= 512u) continue;
        float nr[3][20];
        #pragma unroll
        for (int ch = 0; ch < 3; ++ch)
            #pragma unroll
            for (int tq = 0; tq < 5; ++tq) {
                float4 f = *reinterpret_cast<const float4*>(rgbT + ch * NP + ar * HW + b0 - 8 + 4 * tq);
                nr[ch][4*tq+0] = f.x; nr[ch][4*tq+1] = f.y; nr[ch][4*tq+2] = f.z; nr[ch][4*tq+3] = f.w;
            }
        float spk = KB_EXP * (float)(dy * dy);
        u32 wpk[4][7];
        #pragma unroll
        for (int jj = 0; jj < 4; ++jj) {
            float w[13];
            #pragma unroll
            for (int dx = 0; dx < 13; ++dx) {
                int ic = jj + dx + 2;
                float d0 = cr[0][jj] - nr[0][ic];
                float d1 = cr[1][jj] - nr[1][ic];
                float d2 = cr[2][jj] - nr[2][ic];
                float dcol = d0*d0 + d1*d1 + d2*d2;
                float arg = KB_EXP * dcol + (spk + KB_EXP * (float)((dx-6)*(dx-6)));
                bool ok = (unsigned)(b0 + jj + dx - 6) < 512u;
                w[dx] = ok ? fexp2(arg) : 0.f;
            }
            #pragma unroll
            for (int t = 0; t < 6; ++t) wpk[jj][t] = pkrtz(w[2*t], w[2*t+1]);
            wpk[jj][6] = pkrtz(w[12], 0.f);
        }
        #pragma unroll
        for (int ci = 0; ci < 7; ++ci) {
            const uint2* pw = reinterpret_cast<const uint2*>(ph + (size_t)(cbase + ci) * NPIX + ar * HW + b0 - 8);
            uint2 L0 = pw[0], L1 = pw[1], L2 = pw[2], L3 = pw[3], L4 = pw[4];
            u32 W0[10] = {L0.x, L0.y, L1.x, L1.y, L2.x, L2.y, L3.x, L3.y, L4.x, L4.y};
            u32 W1[9];
            #pragma unroll
            for (int k = 1; k < 9; ++k) W1[k] = (W0[k] >> 16) | (W0[k+1] << 16);
            acc[ci][0] = dot7(wpk[0], W0 + 1, acc[ci][0]);
            acc[ci][1] = dot7(wpk[1], W1 + 1, acc[ci][1]);
            acc[ci][2] = dot7(wpk[2], W0 + 2, acc[ci][2]);
            acc[ci][3] = dot7(wpk[3], W1 + 2, acc[ci][3]);
        }
    }
    float* dst = z ? P1 : P0;
    #pragma unroll
    for (int ci = 0; ci < 7; ++ci) {
        float4 r;
        r.x = acc[ci][0]; r.y = acc[ci][1]; r.z = acc[ci][2]; r.w = acc[ci][3];
        *reinterpret_cast<float4*>(dst + (cbase + ci) * NP + a * HW + b0) = r;
    }
}

__global__ void k_combine(const float* __restrict__ u, const _Float16* __restrict__ sp,
                          const float* __restrict__ P0, const float* __restrict__ P1,
                          const float* __restrict__ inorm,
                          const float* __restrict__ M1, const float* __restrict__ M2,
                          float* __restrict__ q) {
    __shared__ float m1[NC * NC], m2[NC * NC];
    int t = threadIdx.x;
    for (int i = t; i < NC * NC; i += 256) { m1[i] = M1[i]; m2[i] = M2[i]; }
    __syncthreads();
    int px = blockIdx.x * 256 + t;
    float rn = inorm[px];
    float msg[NC];
    #pragma unroll
    for (int c = 0; c < NC; ++c) msg[c] = 0.f;
    #pragma unroll 3
    for (int k = 0; k < NC; ++k) {
        float s = (float)sp[(size_t)k * NPIX + px];
        float b = (P0[k * NP + px] + P1[k * NP + px]) * rn;
        #pragma unroll
        for (int c = 0; c < NC; ++c) msg[c] += m1[c * NC + k] * s + m2[c * NC + k] * b;
    }
    #pragma unroll
    for (int c = 0; c < NC; ++c) q[c * NP + px] = u[c * NP + px] + msg[c];
}

__global__ void k_output(const float* __restrict__ q, float* __restrict__ out) {
    __shared__ float tile[256 * NC];
    int t = threadIdx.x;
    int p0 = blockIdx.x * 256;
    #pragma unroll
    for (int c = 0; c < NC; ++c) tile[t * NC + c] = q[c * NP + p0 + t];
    __syncthreads();
    for (int i = t; i < 256 * NC; i += 256) out[(size_t)p0 * NC + i] = tile[i];
}

extern "C" void kernel_launch(void* const* d_in, const int* in_sizes, int n_in,
                              void* d_out, int out_size, void* d_ws, size_t ws_size,
                              hipStream_t stream) {
    const float* unaries = (const float*)d_in[0];
    const float* rgb     = (const float*)d_in[1];
    const float* Wsp     = (const float*)d_in[2];
    const float* Wbl     = (const float*)d_in[3];
    const float* Cm      = (const float*)d_in[4];
    float* out = (float*)d_out;
    float* ws  = (float*)d_ws;

    const size_t PHF  = ((size_t)NC * NPIX + 128) / 2;       // fp16 region, f32 units
    const size_t WSZ  = (size_t)512 * 13 * 3584;             // ws gate uses fp16 upper bound
    const size_t BASE = (size_t)88 * NP + PHF + 2048;        // proven footprint bound
    const size_t needed_fb   = BASE * sizeof(float);
    const size_t needed_fast = (BASE + WSZ) * sizeof(float);
    if (ws_size < needed_fb) return;
    bool fast = ws_size >= needed_fast;

    if (fast) {
        // layout: u 21 | rgbT 3 | inorm 1 | u16 11 | phsp 11 | sp16 11 | P16 11 | tables | nq 4
        float* u     = ws;
        float* rgbT  = ws + (size_t)21 * NP;
        float* inorm = ws + (size_t)24 * NP;
        _Float16* u16  = (_Float16*)(ws + (size_t)25 * NP) + 64;
        _Float16* phsp = (_Float16*)(ws + (size_t)36 * NP) + 64;
        _Float16* sp16 = (_Float16*)(ws + (size_t)47 * NP) + 64;
        _Float16* P16  = (_Float16*)(ws + (size_t)58 * NP) + 64;
        float* invS  = ws + (size_t)69 * NP;
        float* M1    = invS + 512;
        float* M2    = M1 + 441;
        float* nq    = ws + (size_t)70 * NP;   // 4 partial-norm planes
        u32* wbuf    = (u32*)(ws + BASE);

        k_setup<<<NPIX / 256, 256, 0, stream>>>(unaries, rgb, u, nullptr, rgbT, u16);
        k_prep<<<1, 512, 0, stream>>>(Wsp, Wbl, Cm, invS, M1, M2);
        k_weights_part<<<2048, 128, 0, stream>>>(rgbT, wbuf, nq);
        k_invnorm<<<NPIX / 256, 256, 0, stream>>>(nq, inorm);
        k_softmax<<<NPIX / 4 / 256, 256, 0, stream>>>(u, phsp);   // q0 = u

        for (int it = 0; it < 5; ++it) {
            k_filters<<<1536, 128, 0, stream>>>(phsp, wbuf, invS, P16, sp16);
            k_combine2<<<NPIX / 256, 128, 0, stream>>>(u, u16, sp16, P16, inorm,
                                                       M1, M2, phsp, out, it == 4);
        }
    } else {
        // fallback: exact R7 slow path
        float* u     = ws;
        float* q     = ws + (size_t)21 * NP;
        float* A     = ws + (size_t)42 * NP;
        float* P1    = ws + (size_t)63 * NP;
        float* rgbT  = ws + (size_t)84 * NP;
        float* inorm = ws + (size_t)87 * NP;
        _Float16* ph = (_Float16*)(ws + (size_t)88 * NP) + 64;
        float* invS  = ws + (size_t)88 * NP + PHF;
        float* M1    = invS + 512;
        float* M2    = M1 + 441;
        _Float16* htmp = (_Float16*)q;
        _Float16* sp16 = ph;
        float* nq = P1;

        k_setup<<<NPIX / 256, 256, 0, stream>>>(unaries, rgb, u, q, rgbT, nullptr);
        k_prep<<<1, 512, 0, stream>>>(Wsp, Wbl, Cm, invS, M1, M2);
        k_blnorm_part<<<2048, 128, 0, stream>>>(rgbT, nq);
        k_invnorm<<<NPIX / 256, 256, 0, stream>>>(nq, inorm);

        for (int it = 0; it < 5; ++it) {
            k_softmax<<<NPIX / 4 / 256, 256, 0, stream>>>(q, ph);
            k_spatial_h<<<(NC * 512 * 128) / 256, 256, 0, stream>>>(ph, htmp);
            k_bilateral<<<3072, 128, 0, stream>>>(ph, rgbT, A, P1);
            k_spatial_v<<<(NC * 512 * 128) / 256, 256, 0, stream>>>(htmp, sp16, invS);
            k_combine<<<NPIX / 256, 256, 0, stream>>>(u, sp16, A, P1, inorm, M1, M2, q);
        }
        k_output<<<NPIX / 256, 256, 0, stream>>>(q, out);
    }
}

// Round 17
// 459.349 us; speedup vs baseline: 1.0209x; 1.0209x over previous
//
#include <hip/hip_runtime.h>
#include <cstddef>

#define HW   512
#define NPIX (HW*HW)
#define NP   (NPIX + 64)     // f32 plane stride
#define NC   21

typedef unsigned int u32;
typedef __fp16 h2 __attribute__((ext_vector_type(2)));

__device__ __forceinline__ float fexp2(float x) { return __builtin_amdgcn_exp2f(x); }
__device__ __forceinline__ h2 as_h2(u32 x) { union { u32 u; h2 h; } v; v.u = x; return v.h; }
__device__ __forceinline__ u32 as_u32(h2 x) { union { h2 h; u32 u; } v; v.h = x; return v.u; }
__device__ __forceinline__ u32 pkrtz(float a, float b) { return as_u32(__builtin_amdgcn_cvt_pkrtz(a, b)); }

// dot over 7 packed fp16 pairs: s += sum_t w[t] . a[t]
__device__ __forceinline__ float dot7(const u32* w, const u32* a, float s) {
    #pragma unroll
    for (int t = 0; t < 7; ++t)
        s = __builtin_amdgcn_fdot2(as_h2(w[t]), as_h2(a[t]), s, false);
    return s;
}

#define KB_EXP (-0.08014972449f)          /* -0.5/9 * log2(e) */
#define LOG2E  (1.4426950408889634f)

#define KSP_INIT {0.13533528f, 0.24935221f, 0.41111229f, 0.60653066f, 0.80073740f, \
                  0.94595947f, 1.00000000f, 0.94595947f, 0.80073740f, 0.60653066f, \
                  0.41111229f, 0.24935221f, 0.13533528f}

// ---------- setup ----------
__global__ void k_setup(const float* __restrict__ unaries, const float* __restrict__ rgb,
                        float* __restrict__ u, float* q, float* __restrict__ rgbT,
                        _Float16* u16) {
    int p = blockIdx.x * 256 + threadIdx.x;       // p = a*512 + b
    int a = p >> 9, b = p & 511;
    int src = b * 512 + a;
    #pragma unroll
    for (int c = 0; c < NC; ++c) {
        float v = unaries[src * NC + c];
        u[c * NP + p] = v;
        if (q)   q[c * NP + p] = v;
        if (u16) u16[(size_t)c * NPIX + p] = (_Float16)v;
    }
    #pragma unroll
    for (int ch = 0; ch < 3; ++ch) rgbT[ch * NP + p] = rgb[src * 3 + ch];
}

// ---------- prep ----------
__global__ void k_prep(const float* __restrict__ Wsp, const float* __restrict__ Wbl,
                       const float* __restrict__ Cm,
                       float* __restrict__ invS, float* __restrict__ M1, float* __restrict__ M2) {
    int t = threadIdx.x;
    const float KSP[13] = KSP_INIT;
    {
        float s = 0.f;
        #pragma unroll
        for (int d = 0; d < 13; ++d) {
            int i = t + d - 6;
            if ((unsigned)i < 512u) s += KSP[d];
        }
        invS[t] = 1.0f / s;
    }
    if (t < NC * NC) {
        int c = t / NC, j = t % NC;
        float s1 = 0.f, s2 = 0.f;
        for (int k = 0; k < NC; ++k) {
            float cm = Cm[c * NC + k];
            s1 += cm * Wsp[k * NC + j];
            s2 += cm * Wbl[k * NC + j];
        }
        M1[t] = -s1;
        M2[t] = -s2;
    }
}

// ---------- one-time: precompute bilateral weights (fp16 pairs), 4 dy-quarters ----------
// grid 2048 = 512 rows x 4 quarters; partial Sum(w) -> nq[z] plane; slots unchanged.
__global__ void k_weights_part(const float* __restrict__ rgbT, u32* __restrict__ wbuf,
                               float* __restrict__ nq) {
    int bid = blockIdx.x;
    int z = bid >> 9, a = bid & 511;
    int b0 = threadIdx.x << 2;
    float cr[3][4];
    #pragma unroll
    for (int ch = 0; ch < 3; ++ch) {
        float4 f = *reinterpret_cast<const float4*>(rgbT + ch * NP + a * HW + b0);
        cr[ch][0] = f.x; cr[ch][1] = f.y; cr[ch][2] = f.z; cr[ch][3] = f.w;
    }
    float nsum[4] = {0.f, 0.f, 0.f, 0.f};
    const int dlos[4] = {0, 3, 7, 10};
    const int dhis[4] = {3, 7, 10, 13};
    int dlo = dlos[z], dhi = dhis[z];
    #pragma unroll 1
    for (int dyi = dlo; dyi < dhi; ++dyi) {
        int ar = a + dyi - 6;
        if ((unsigned)ar >= 512u) continue;
        float nr[3][20];
        #pragma unroll
        for (int ch = 0; ch < 3; ++ch)
            #pragma unroll
            for (int tq = 0; tq < 5; ++tq) {
                float4 f = *reinterpret_cast<const float4*>(rgbT + ch * NP + ar * HW + b0 - 8 + 4 * tq);
                nr[ch][4*tq+0] = f.x; nr[ch][4*tq+1] = f.y; nr[ch][4*tq+2] = f.z; nr[ch][4*tq+3] = f.w;
            }
        float spk = KB_EXP * (float)((dyi - 6) * (dyi - 6));
        u32 arr[28];
        #pragma unroll
        for (int j = 0; j < 4; ++j) {
            float w[13];
            #pragma unroll
            for (int dx = 0; dx < 13; ++dx) {
                int ic = j + dx + 2;
                float d0 = cr[0][j] - nr[0][ic];
                float d1 = cr[1][j] - nr[1][ic];
                float d2 = cr[2][j] - nr[2][ic];
                float dcol = d0*d0 + d1*d1 + d2*d2;
                float arg = KB_EXP * dcol + (spk + KB_EXP * (float)((dx-6)*(dx-6)));
                bool ok = (unsigned)(b0 + j + dx - 6) < 512u;
                w[dx] = ok ? fexp2(arg) : 0.f;
                nsum[j] += w[dx];
            }
            #pragma unroll
            for (int t = 0; t < 6; ++t) arr[j*7+t] = pkrtz(w[2*t], w[2*t+1]);
            arr[j*7+6] = pkrtz(w[12], 0.f);
        }
        uint4* dst = reinterpret_cast<uint4*>(wbuf) + ((size_t)(a * 13 + dyi) * 896 + threadIdx.x * 7);
        #pragma unroll
        for (int k = 0; k < 7; ++k)
            dst[k] = make_uint4(arr[4*k], arr[4*k+1], arr[4*k+2], arr[4*k+3]);
    }
    float4 r; r.x = nsum[0]; r.y = nsum[1]; r.z = nsum[2]; r.w = nsum[3];
    *reinterpret_cast<float4*>(nq + (size_t)z * NP + a * HW + b0) = r;
}

__global__ void k_invnorm(const float* __restrict__ nq, float* __restrict__ inorm) {
    int i = blockIdx.x * 256 + threadIdx.x;
    inorm[i] = 1.0f / (nq[i] + nq[NP + i] + nq[2 * (size_t)NP + i] + nq[3 * (size_t)NP + i]);
}

// ---------- fused per-iter filters: bilateral (from wbuf) + non-separable spatial ----------
// grid 1536 = 8 XCD x (64 rows x 3 chunks); 128 thr, 4 px/thread, all 13 dy.
__global__ __launch_bounds__(128, 3)
void k_filters(const _Float16* __restrict__ ph, const u32* __restrict__ wbuf,
               const float* __restrict__ invS,
               _Float16* __restrict__ P, _Float16* __restrict__ SP) {
    int bid = blockIdx.x;
    int xj = bid & 7;          // XCD
    int g  = bid >> 3;         // 0..191
    int rl = g / 3;            // local row
    int y  = g - rl * 3;       // chunk
    int a  = xj * 64 + rl;
    int cbase = y * 7;
    int tid = threadIdx.x;
    int b0  = tid << 2;

    // spatial packed weights, per-j edge-masked (same dot7 alignment as bilateral)
    const float KSP[13] = KSP_INIT;
    u32 kp[4][7];
    #pragma unroll
    for (int j = 0; j < 4; ++j) {
        float wj[13];
        #pragma unroll
        for (int dx = 0; dx < 13; ++dx) {
            bool ok = (unsigned)(b0 + j + dx - 6) < 512u;
            wj[dx] = ok ? KSP[dx] : 0.f;
        }
        #pragma unroll
        for (int t = 0; t < 6; ++t) kp[j][t] = pkrtz(wj[2*t], wj[2*t+1]);
        kp[j][6] = pkrtz(wj[12], 0.f);
    }

    float acc[7][4], spa[7][4];
    #pragma unroll
    for (int ci = 0; ci < 7; ++ci)
        #pragma unroll
        for (int j = 0; j < 4; ++j) { acc[ci][j] = 0.f; spa[ci][j] = 0.f; }

    #pragma unroll 1
    for (int dyi = 0; dyi < 13; ++dyi) {
        int ar = a + dyi - 6;
        if ((unsigned)ar >= 512u) continue;
        float kdy = fexp2(KB_EXP * (float)((dyi - 6) * (dyi - 6)));
        const uint4* wp = reinterpret_cast<const uint4*>(wbuf) + ((size_t)(a * 13 + dyi) * 896 + tid * 7);
        u32 arr[28];
        #pragma unroll
        for (int k = 0; k < 7; ++k) {
            uint4 wv = wp[k];
            arr[4*k] = wv.x; arr[4*k+1] = wv.y; arr[4*k+2] = wv.z; arr[4*k+3] = wv.w;
        }
        #pragma unroll
        for (int ci = 0; ci < 7; ++ci) {
            const uint2* pw = reinterpret_cast<const uint2*>(ph + (size_t)(cbase + ci) * NPIX + ar * HW + b0 - 8);
            uint2 L0 = pw[0], L1 = pw[1], L2 = pw[2], L3 = pw[3], L4 = pw[4];
            u32 W0[10] = {L0.x, L0.y, L1.x, L1.y, L2.x, L2.y, L3.x, L3.y, L4.x, L4.y};
            u32 W1[9];
            #pragma unroll
            for (int k = 1; k < 9; ++k) W1[k] = (W0[k] >> 16) | (W0[k+1] << 16);
            acc[ci][0] = dot7(arr + 0,  W0 + 1, acc[ci][0]);
            acc[ci][1] = dot7(arr + 7,  W1 + 1, acc[ci][1]);
            acc[ci][2] = dot7(arr + 14, W0 + 2, acc[ci][2]);
            acc[ci][3] = dot7(arr + 21, W1 + 2, acc[ci][3]);
            spa[ci][0] = fmaf(kdy, dot7(kp[0], W0 + 1, 0.f), spa[ci][0]);
            spa[ci][1] = fmaf(kdy, dot7(kp[1], W1 + 1, 0.f), spa[ci][1]);
            spa[ci][2] = fmaf(kdy, dot7(kp[2], W0 + 2, 0.f), spa[ci][2]);
            spa[ci][3] = fmaf(kdy, dot7(kp[3], W1 + 2, 0.f), spa[ci][3]);
        }
    }
    float isa = invS[a];
    float4 iv = *reinterpret_cast<const float4*>(invS + b0);
    #pragma unroll
    for (int ci = 0; ci < 7; ++ci) {
        uint2 st;
        st.x = pkrtz(acc[ci][0], acc[ci][1]);
        st.y = pkrtz(acc[ci][2], acc[ci][3]);
        *reinterpret_cast<uint2*>(P + (size_t)(cbase + ci) * NPIX + a * HW + b0) = st;
        uint2 ss;
        ss.x = pkrtz(spa[ci][0] * isa * iv.x, spa[ci][1] * isa * iv.y);
        ss.y = pkrtz(spa[ci][2] * isa * iv.z, spa[ci][3] * isa * iv.w);
        *reinterpret_cast<uint2*>(SP + (size_t)(cbase + ci) * NPIX + a * HW + b0) = ss;
    }
}

// ---------- fused combine + softmax, 2 px/thread vectorized ----------
__global__ __launch_bounds__(128)
void k_combine2(const float* __restrict__ u, const _Float16* __restrict__ u16,
                const _Float16* __restrict__ sp, const _Float16* __restrict__ P,
                const float* __restrict__ inorm,
                const float* __restrict__ M1, const float* __restrict__ M2,
                _Float16* __restrict__ phout, float* __restrict__ out, int last) {
    __shared__ float m1[NC * NC], m2[NC * NC];
    int t = threadIdx.x;
    for (int i = t; i < NC * NC; i += 128) { m1[i] = M1[i]; m2[i] = M2[i]; }
    __syncthreads();
    int px = (blockIdx.x * 128 + t) << 1;
    float2 rn = *reinterpret_cast<const float2*>(inorm + px);
    float msg[NC][2];
    #pragma unroll
    for (int c = 0; c < NC; ++c) { msg[c][0] = 0.f; msg[c][1] = 0.f; }
    #pragma unroll 3
    for (int k = 0; k < NC; ++k) {
        h2 sh = as_h2(*reinterpret_cast<const u32*>(sp + (size_t)k * NPIX + px));
        h2 bh = as_h2(*reinterpret_cast<const u32*>(P  + (size_t)k * NPIX + px));
        float s0 = (float)sh[0], s1 = (float)sh[1];
        float b0 = (float)bh[0] * rn.x, b1 = (float)bh[1] * rn.y;
        #pragma unroll
        for (int c = 0; c < NC; ++c) {
            float a1 = m1[c * NC + k], a2 = m2[c * NC + k];
            msg[c][0] += a1 * s0 + a2 * b0;
            msg[c][1] += a1 * s1 + a2 * b1;
        }
    }
    if (last) {
        #pragma unroll
        for (int c = 0; c < NC; ++c) {
            float2 uu = *reinterpret_cast<const float2*>(u + c * NP + px);
            out[(size_t)px * NC + c]       = uu.x + msg[c][0];
            out[(size_t)(px + 1) * NC + c] = uu.y + msg[c][1];
        }
    } else {
        float q0[NC], q1[NC];
        #pragma unroll
        for (int c = 0; c < NC; ++c) {
            h2 uh = as_h2(*reinterpret_cast<const u32*>(u16 + (size_t)c * NPIX + px));
            q0[c] = (float)uh[0] + msg[c][0];
            q1[c] = (float)uh[1] + msg[c][1];
        }
        float m0 = -1e30f, m1v = -1e30f;
        #pragma unroll
        for (int c = 0; c < NC; ++c) { m0 = fmaxf(m0, q0[c]); m1v = fmaxf(m1v, q1[c]); }
        float s0 = 0.f, s1 = 0.f;
        #pragma unroll
        for (int c = 0; c < NC; ++c) {
            q0[c] = fexp2((q0[c] - m0) * LOG2E);  s0 += q0[c];
            q1[c] = fexp2((q1[c] - m1v) * LOG2E); s1 += q1[c];
        }
        float r0 = 1.0f / s0, r1 = 1.0f / s1;
        #pragma unroll
        for (int c = 0; c < NC; ++c)
            *reinterpret_cast<u32*>(phout + (size_t)c * NPIX + px) = pkrtz(q0[c] * r0, q1[c] * r1);
    }
}

// ---------- softmax (prologue + fallback), 4 px/thread ----------
__global__ void k_softmax(const float* __restrict__ q, _Float16* __restrict__ ph) {
    int i4 = (blockIdx.x * 256 + threadIdx.x) << 2;
    float v[NC][4];
    float m[4] = {-1e30f, -1e30f, -1e30f, -1e30f};
    #pragma unroll
    for (int c = 0; c < NC; ++c) {
        float4 f = *reinterpret_cast<const float4*>(q + c * NP + i4);
        v[c][0] = f.x; v[c][1] = f.y; v[c][2] = f.z; v[c][3] = f.w;
        #pragma unroll
        for (int j = 0; j < 4; ++j) m[j] = fmaxf(m[j], v[c][j]);
    }
    float s[4] = {0.f, 0.f, 0.f, 0.f};
    #pragma unroll
    for (int c = 0; c < NC; ++c)
        #pragma unroll
        for (int j = 0; j < 4; ++j) { v[c][j] = fexp2((v[c][j] - m[j]) * LOG2E); s[j] += v[c][j]; }
    float r[4];
    #pragma unroll
    for (int j = 0; j < 4; ++j) r[j] = 1.0f / s[j];
    #pragma unroll
    for (int c = 0; c < NC; ++c) {
        uint2 st;
        st.x = pkrtz(v[c][0] * r[0], v[c][1] * r[1]);
        st.y = pkrtz(v[c][2] * r[2], v[c][3] * r[3]);
        *reinterpret_cast<uint2*>(ph + (size_t)c * NPIX + i4) = st;
    }
}

// ================= fallback path kernels (ws too small for weight table) =================
__global__ void k_blnorm_part(const float* __restrict__ rgbT, float* __restrict__ nq) {
    int bid = blockIdx.x;
    int z = bid >> 9, a = bid & 511;
    int b0 = threadIdx.x << 2;
    float cr[3][4];
    #pragma unroll
    for (int ch = 0; ch < 3; ++ch) {
        float4 f = *reinterpret_cast<const float4*>(rgbT + ch * NP + a * HW + b0);
        cr[ch][0] = f.x; cr[ch][1] = f.y; cr[ch][2] = f.z; cr[ch][3] = f.w;
    }
    float sum[4] = {0.f, 0.f, 0.f, 0.f};
    const int dylos[4] = {-6, -3, 1, 4};
    const int dyhis[4] = {-4,  0, 3, 6};
    int dylo = dylos[z], dyhi = dyhis[z];
    #pragma unroll 1
    for (int dy = dylo; dy <= dyhi; ++dy) {
        int ar = a + dy;
        if ((unsigned)ar >= 512u) continue;
        int rowoff = ar * HW + b0 - 8;
        float nr[3][20];
        #pragma unroll
        for (int ch = 0; ch < 3; ++ch)
            #pragma unroll
            for (int tq = 0; tq < 5; ++tq) {
                float4 f = *reinterpret_cast<const float4*>(rgbT + ch * NP + rowoff + 4 * tq);
                nr[ch][4*tq+0] = f.x; nr[ch][4*tq+1] = f.y; nr[ch][4*tq+2] = f.z; nr[ch][4*tq+3] = f.w;
            }
        float spk = KB_EXP * (float)(dy * dy);
        #pragma unroll
        for (int j = 0; j < 4; ++j) {
            #pragma unroll
            for (int dx = 0; dx < 13; ++dx) {
                int ic = j + dx + 2;
                float d0 = cr[0][j] - nr[0][ic];
                float d1 = cr[1][j] - nr[1][ic];
                float d2 = cr[2][j] - nr[2][ic];
                float dcol = d0*d0 + d1*d1 + d2*d2;
                float arg = KB_EXP * dcol + (spk + KB_EXP * (float)((dx-6)*(dx-6)));
                bool ok = (unsigned)(b0 + j + dx - 6) < 512u;
                sum[j] += ok ? fexp2(arg) : 0.f;
            }
        }
    }
    float4 r; r.x = sum[0]; r.y = sum[1]; r.z = sum[2]; r.w = sum[3];
    *reinterpret_cast<float4*>(nq + (size_t)z * NP + a * HW + b0) = r;
}

__global__ void k_spatial_h(const _Float16* __restrict__ ph, _Float16* __restrict__ dst) {
    int idx = blockIdx.x * 256 + threadIdx.x;
    int b0 = (idx & 127) << 2;
    int a  = (idx >> 7) & 511;
    int c  = idx >> 16;
    const uint2* pw = reinterpret_cast<const uint2*>(ph + (size_t)c * NPIX + a * HW + b0 - 8);
    uint2 L0 = pw[0], L1 = pw[1], L2 = pw[2], L3 = pw[3], L4 = pw[4];
    u32 W0[10] = {L0.x, L0.y, L1.x, L1.y, L2.x, L2.y, L3.x, L3.y, L4.x, L4.y};
    const float KSP[13] = KSP_INIT;
    float out[4];
    if (b0 >= 8 && b0 <= 500) {
        u32 W1[9];
        #pragma unroll
        for (int k = 1; k < 9; ++k) W1[k] = (W0[k] >> 16) | (W0[k+1] << 16);
        u32 kp[7];
        #pragma unroll
        for (int t = 0; t < 6; ++t) kp[t] = pkrtz(KSP[2*t], KSP[2*t+1]);
        kp[6] = pkrtz(KSP[12], 0.f);
        out[0] = dot7(kp, W0 + 1, 0.f);
        out[1] = dot7(kp, W1 + 1, 0.f);
        out[2] = dot7(kp, W0 + 2, 0.f);
        out[3] = dot7(kp, W1 + 2, 0.f);
    } else {
        float pv[20];
        #pragma unroll
        for (int k = 0; k < 10; ++k) { h2 hh = as_h2(W0[k]); pv[2*k] = (float)hh[0]; pv[2*k+1] = (float)hh[1]; }
        #pragma unroll
        for (int j = 0; j < 4; ++j) out[j] = 0.f;
        #pragma unroll
        for (int d = 0; d < 13; ++d)
            #pragma unroll
            for (int j = 0; j < 4; ++j) {
                bool ok = (unsigned)(b0 + j + d - 6) < 512u;
                out[j] += (ok ? KSP[d] : 0.f) * pv[j + d + 2];
            }
    }
    uint2 st;
    st.x = pkrtz(out[0], out[1]);
    st.y = pkrtz(out[2], out[3]);
    *reinterpret_cast<uint2*>(dst + (size_t)c * NPIX + a * HW + b0) = st;
}

__global__ void k_spatial_v(const _Float16* __restrict__ src, _Float16* __restrict__ dst,
                            const float* __restrict__ invS) {
    int idx = blockIdx.x * 256 + threadIdx.x;
    int b0 = (idx & 127) << 2;
    int a  = (idx >> 7) & 511;
    int c  = idx >> 16;
    const float KSP[13] = KSP_INIT;
    float out[4] = {0.f, 0.f, 0.f, 0.f};
    #pragma unroll
    for (int d = 0; d < 13; ++d) {
        int ar = a + d - 6;
        if ((unsigned)ar < 512u) {
            uint2 L = *reinterpret_cast<const uint2*>(src + (size_t)c * NPIX + ar * HW + b0);
            h2 h0 = as_h2(L.x), h1 = as_h2(L.y);
            out[0] += KSP[d] * (float)h0[0]; out[1] += KSP[d] * (float)h0[1];
            out[2] += KSP[d] * (float)h1[0]; out[3] += KSP[d] * (float)h1[1];
        }
    }
    float isa = invS[a];
    float4 iv = *reinterpret_cast<const float4*>(invS + b0);
    uint2 st;
    st.x = pkrtz(out[0] * isa * iv.x, out[1] * isa * iv.y);
    st.y = pkrtz(out[2] * isa * iv.z, out[3] * isa * iv.w);
    *reinterpret_cast<uint2*>(dst + (size_t)c * NPIX + a * HW + b0) = st;
}

__global__ __launch_bounds__(128, 4)
void k_bilateral(const _Float16* __restrict__ ph, const float* __restrict__ rgbT,
                 float* __restrict__ P0, float* __restrict__ P1) {
    int bid = blockIdx.x;
    int xj = bid & 7;
    int g  = bid >> 3;
    int rl = g / 6;
    int v  = g - rl * 6;
    int a  = xj * 64 + rl;
    int y  = v >> 1;
    int z  = v & 1;
    int cbase = y * 7;
    int b0  = threadIdx.x << 2;
    float cr[3][4];
    #pragma unroll
    for (int ch = 0; ch < 3; ++ch) {
        float4 f = *reinterpret_cast<const float4*>(rgbT + ch * NP + a * HW + b0);
        cr[ch][0] = f.x; cr[ch][1] = f.y; cr[ch][2] = f.z; cr[ch][3] = f.w;
    }
    float acc[7][4];
    #pragma unroll
    for (int ci = 0; ci < 7; ++ci)
        #pragma unroll
        for (int j2 = 0; j2 < 4; ++j2) acc[ci][j2] = 0.f;

    int dylo = z ? 1 : -6, dyhi = z ? 6 : 0;
    #pragma unroll 1
    for (int dy = dylo; dy <= dyhi; ++dy) {
        int ar = a + dy;
        if ((unsigned)ar >= 512u) continue;
        float nr[3][20];
        #pragma unroll
        for (int ch = 0; ch < 3; ++ch)
            #pragma unroll
            for (int tq = 0; tq < 5; ++tq) {
                float4 f = *reinterpret_cast<const float4*>(rgbT + ch * NP + ar * HW + b0 - 8 + 4 * tq);
                nr[ch][4*tq+0] = f.x; nr[ch][4*tq+1] = f.y; nr[ch][4*tq+2] = f.z; nr[ch][4*tq+3] = f.w;
            }
        float spk = KB_EXP * (float)(dy * dy);
        u32 wpk[4][7];
        #pragma unroll
        for (int jj = 0; jj < 4; ++jj) {
            float w[13];
            #pragma unroll
            for (int dx = 0; dx < 13; ++dx) {
                int ic = jj + dx + 2;
                float d0 = cr[0][jj] - nr[0][ic];
                float d1 = cr[1][jj] - nr[1][ic];
                float d2 = cr[2][jj] - nr[2][ic];
                float dcol = d0*d0 + d1*d1 + d2*d2;
                float arg = KB_EXP * dcol + (spk + KB_EXP * (float)((dx-6)*(dx-6)));
                bool ok = (unsigned)(b0 + jj + dx - 6) < 512u;
                w[dx] = ok ? fexp2(arg) : 0.f;
            }
            #pragma unroll
            for (int t = 0; t < 6; ++t) wpk[jj][t] = pkrtz(w[2*t], w[2*t+1]);
            wpk[jj][6] = pkrtz(w[12], 0.f);
        }
        #pragma unroll
        for (int ci = 0; ci < 7; ++ci) {
            const uint2* pw = reinterpret_cast<const uint2*>(ph + (size_t)(cbase + ci) * NPIX + ar * HW + b0 - 8);
            uint2 L0 = pw[0], L1 = pw[1], L2 = pw[2], L3 = pw[3], L4 = pw[4];
            u32 W0[10] = {L0.x, L0.y, L1.x, L1.y, L2.x, L2.y, L3.x, L3.y, L4.x, L4.y};
            u32 W1[9];
            #pragma unroll
            for (int k = 1; k < 9; ++k) W1[k] = (W0[k] >> 16) | (W0[k+1] << 16);
            acc[ci][0] = dot7(wpk[0], W0 + 1, acc[ci][0]);
            acc[ci][1] = dot7(wpk[1], W1 + 1, acc[ci][1]);
            acc[ci][2] = dot7(wpk[2], W0 + 2, acc[ci][2]);
            acc[ci][3] = dot7(wpk[3], W1 + 2, acc[ci][3]);
        }
    }
    float* dst = z ? P1 : P0;
    #pragma unroll
    for (int ci = 0; ci < 7; ++ci) {
        float4 r;
        r.x = acc[ci][0]; r.y = acc[ci][1]; r.z = acc[ci][2]; r.w = acc[ci][3];
        *reinterpret_cast<float4*>(dst + (cbase + ci) * NP + a * HW + b0) = r;
    }
}

__global__ void k_combine(const float* __restrict__ u, const _Float16* __restrict__ sp,
                          const float* __restrict__ P0, const float* __restrict__ P1,
                          const float* __restrict__ inorm,
                          const float* __restrict__ M1, const float* __restrict__ M2,
                          float* __restrict__ q) {
    __shared__ float m1[NC * NC], m2[NC * NC];
    int t = threadIdx.x;
    for (int i = t; i < NC * NC; i += 256) { m1[i] = M1[i]; m2[i] = M2[i]; }
    __syncthreads();
    int px = blockIdx.x * 256 + t;
    float rn = inorm[px];
    float msg[NC];
    #pragma unroll
    for (int c = 0; c < NC; ++c) msg[c] = 0.f;
    #pragma unroll 3
    for (int k = 0; k < NC; ++k) {
        float s = (float)sp[(size_t)k * NPIX + px];
        float b = (P0[k * NP + px] + P1[k * NP + px]) * rn;
        #pragma unroll
        for (int c = 0; c < NC; ++c) msg[c] += m1[c * NC + k] * s + m2[c * NC + k] * b;
    }
    #pragma unroll
    for (int c = 0; c < NC; ++c) q[c * NP + px] = u[c * NP + px] + msg[c];
}

__global__ void k_output(const float* __restrict__ q, float* __restrict__ out) {
    __shared__ float tile[256 * NC];
    int t = threadIdx.x;
    int p0 = blockIdx.x * 256;
    #pragma unroll
    for (int c = 0; c < NC; ++c) tile[t * NC + c] = q[c * NP + p0 + t];
    __syncthreads();
    for (int i = t; i < 256 * NC; i += 256) out[(size_t)p0 * NC + i] = tile[i];
}

extern "C" void kernel_launch(void* const* d_in, const int* in_sizes, int n_in,
                              void* d_out, int out_size, void* d_ws, size_t ws_size,
                              hipStream_t stream) {
    const float* unaries = (const float*)d_in[0];
    const float* rgb     = (const float*)d_in[1];
    const float* Wsp     = (const float*)d_in[2];
    const float* Wbl     = (const float*)d_in[3];
    const float* Cm      = (const float*)d_in[4];
    float* out = (float*)d_out;
    float* ws  = (float*)d_ws;

    const size_t PHF  = ((size_t)NC * NPIX + 128) / 2;       // fp16 region, f32 units
    const size_t WSZ  = (size_t)512 * 13 * 3584;             // weight table, u32 units
    const size_t BASE = (size_t)88 * NP + PHF + 2048;        // proven footprint bound
    const size_t needed_fb   = BASE * sizeof(float);
    const size_t needed_fast = (BASE + WSZ) * sizeof(float);
    if (ws_size < needed_fb) return;
    bool fast = ws_size >= needed_fast;

    if (fast) {
        // layout: u 21 | rgbT 3 | inorm 1 | u16 11 | phsp 11 | sp16 11 | P16 11 | tables | nq 4
        float* u     = ws;
        float* rgbT  = ws + (size_t)21 * NP;
        float* inorm = ws + (size_t)24 * NP;
        _Float16* u16  = (_Float16*)(ws + (size_t)25 * NP) + 64;
        _Float16* phsp = (_Float16*)(ws + (size_t)36 * NP) + 64;
        _Float16* sp16 = (_Float16*)(ws + (size_t)47 * NP) + 64;
        _Float16* P16  = (_Float16*)(ws + (size_t)58 * NP) + 64;
        float* invS  = ws + (size_t)69 * NP;
        float* M1    = invS + 512;
        float* M2    = M1 + 441;
        float* nq    = ws + (size_t)70 * NP;   // 4 partial-norm planes
        u32* wbuf    = (u32*)(ws + BASE);

        k_setup<<<NPIX / 256, 256, 0, stream>>>(unaries, rgb, u, nullptr, rgbT, u16);
        k_prep<<<1, 512, 0, stream>>>(Wsp, Wbl, Cm, invS, M1, M2);
        k_weights_part<<<2048, 128, 0, stream>>>(rgbT, wbuf, nq);
        k_invnorm<<<NPIX / 256, 256, 0, stream>>>(nq, inorm);
        k_softmax<<<NPIX / 4 / 256, 256, 0, stream>>>(u, phsp);   // q0 = u

        for (int it = 0; it < 5; ++it) {
            k_filters<<<1536, 128, 0, stream>>>(phsp, wbuf, invS, P16, sp16);
            k_combine2<<<NPIX / 256, 128, 0, stream>>>(u, u16, sp16, P16, inorm,
                                                       M1, M2, phsp, out, it == 4);
        }
    } else {
        // fallback: exact R7 slow path
        float* u     = ws;
        float* q     = ws + (size_t)21 * NP;
        float* A     = ws + (size_t)42 * NP;
        float* P1    = ws + (size_t)63 * NP;
        float* rgbT  = ws + (size_t)84 * NP;
        float* inorm = ws + (size_t)87 * NP;
        _Float16* ph = (_Float16*)(ws + (size_t)88 * NP) + 64;
        float* invS  = ws + (size_t)88 * NP + PHF;
        float* M1    = invS + 512;
        float* M2    = M1 + 441;
        _Float16* htmp = (_Float16*)q;
        _Float16* sp16 = ph;
        float* nq = P1;

        k_setup<<<NPIX / 256, 256, 0, stream>>>(unaries, rgb, u, q, rgbT, nullptr);
        k_prep<<<1, 512, 0, stream>>>(Wsp, Wbl, Cm, invS, M1, M2);
        k_blnorm_part<<<2048, 128, 0, stream>>>(rgbT, nq);
        k_invnorm<<<NPIX / 256, 256, 0, stream>>>(nq, inorm);

        for (int it = 0; it < 5; ++it) {
            k_softmax<<<NPIX / 4 / 256, 256, 0, stream>>>(q, ph);
            k_spatial_h<<<(NC * 512 * 128) / 256, 256, 0, stream>>>(ph, htmp);
            k_bilateral<<<3072, 128, 0, stream>>>(ph, rgbT, A, P1);
            k_spatial_v<<<(NC * 512 * 128) / 256, 256, 0, stream>>>(htmp, sp16, invS);
            k_combine<<<NPIX / 256, 256, 0, stream>>>(u, sp16, A, P1, inorm, M1, M2, q);
        }
        k_output<<<NPIX / 256, 256, 0, stream>>>(q, out);
    }
}